// Round 4
// baseline (593.211 us; speedup 1.0000x reference)
//
#include <hip/hip_runtime.h>

typedef unsigned short u16;
typedef unsigned int u32;

#define D_DIM 128

__device__ __forceinline__ float bf2f(u16 h) {
    u32 u = ((u32)h) << 16;
    return __uint_as_float(u);
}
__device__ __forceinline__ u16 f2bf(float f) {
    u32 u = __float_as_uint(f);
    u32 r = (u >> 16) & 1u;
    u += 0x7fffu + r;                 // round-to-nearest-even
    return (u16)(u >> 16);
}
__device__ __forceinline__ float lo16(u32 u) { return bf2f((u16)(u & 0xffffu)); }
__device__ __forceinline__ float hi16(u32 u) { return bf2f((u16)(u >> 16)); }

// --- K0: dtype detector. bf16-packed words: low-half bits 14..7 are a bf16
// exponent, ~always in [100,140] for N(0,1) data. fp32 words: those bits are
// mantissa noise (~16% in range). 1024 words sampled -> flag 1=bf16, 0=fp32.
__global__ void k_detect(const u32* w, int* flag) {
    __shared__ int cnt;
    if (threadIdx.x == 0) cnt = 0;
    __syncthreads();
    int c = 0;
    for (int j = 0; j < 4; ++j) {
        u32 x = w[threadIdx.x * 4 + j];
        u32 e = (x >> 7) & 0xFFu;
        if (e >= 100u && e <= 140u) c++;
    }
    atomicAdd(&cnt, c);
    __syncthreads();
    if (threadIdx.x == 0) flag[0] = (cnt >= 700) ? 1 : 0;
}

// --- K1: sentinel fill of d_out with 100.0 (diagnostic: overwritten later) --
__global__ void k_fill(u32* outw, const int* flag, int out_elems) {
    int bf = flag[0];
    int nwords = bf ? (out_elems / 2) : out_elems;
    u32 pat = bf ? 0x42C842C8u : 0x42C80000u;   // bf16(100)|bf16(100) / fp32(100)
    int i = blockIdx.x * blockDim.x + threadIdx.x;
    if (i < nwords) outw[i] = pat;
}

// --- K2: zero scratch words (harness's expected symbol name kept) -----------
__global__ void GCNLayer_76647986365164_kernel(int* p, int nwords) {
    int i = blockIdx.x * blockDim.x + threadIdx.x;
    if (i < nwords) p[i] = 0;
}

// --- K3: in-degree count ----------------------------------------------------
__global__ void k_deg(const int* dst, int* deg, int E) {
    int i = blockIdx.x * blockDim.x + threadIdx.x;
    if (i < E) atomicAdd(&deg[dst[i]], 1);
}

// --- K4: exclusive prefix scan, single block of 256, 16 elems/thread, LDS ---
__global__ void k_scan(const int* deg, int* offs, int* cursor, int n, int nIter) {
    __shared__ int tsum[256];
    __shared__ int carry;
    const int tid = threadIdx.x;
    if (tid == 0) carry = 0;
    __syncthreads();
    for (int it = 0; it < nIter; ++it) {
        int base = it * 4096 + tid * 16;
        int v[16];
        int run = 0;
        for (int j = 0; j < 16; ++j) {
            int idx = base + j;
            v[j] = (idx < n) ? deg[idx] : 0;
            run += v[j];
        }
        tsum[tid] = run;
        __syncthreads();
        for (int off = 1; off < 256; off <<= 1) {   // Hillis-Steele inclusive
            int val = tsum[tid];
            int add = (tid >= off) ? tsum[tid - off] : 0;
            __syncthreads();
            tsum[tid] = val + add;
            __syncthreads();
        }
        int acc = carry + tsum[tid] - run;          // exclusive start
        for (int j = 0; j < 16; ++j) {
            int idx = base + j;
            if (idx < n) { offs[idx] = acc; cursor[idx] = acc; }
            acc += v[j];
        }
        __syncthreads();
        if (tid == 0) carry += tsum[255];
        __syncthreads();
    }
    if (tid == 0) offs[n] = carry;                  // == E
}

// --- K5: scatter edges into CSR buckets -------------------------------------
__global__ void k_scatter(const int* src, const int* dst,
                          int* cursor, int* csr, int E) {
    int i = blockIdx.x * blockDim.x + threadIdx.x;
    if (i < E) {
        int d = dst[i];
        int pos = atomicAdd(&cursor[d], 1);
        csr[pos] = src[i];
    }
}

// --- K6: gather-reduce mean aggregation, one wave per node, dual dtype ------
__global__ void k_aggregate(const void* feature, const int* offs,
                            const int* csr, u16* agg, const int* flag,
                            int n, int npad) {
    int node = blockIdx.x * 4 + (threadIdx.x >> 6);
    int lane = threadIdx.x & 63;
    if (node >= npad) return;
    int bf = flag[0];
    float a0 = 0.f, a1 = 0.f;
    int degn = 0;
    if (node < n) {
        int s = offs[node], e = offs[node + 1];
        degn = e - s;
        if (bf) {
            const u16* f16 = (const u16*)feature;
            for (int j = s; j < e; ++j) {
                int sn = csr[j];
                u32 u = ((const u32*)(f16 + (size_t)sn * D_DIM))[lane];
                a0 += lo16(u);
                a1 += hi16(u);
            }
        } else {
            const float* ff = (const float*)feature;
            for (int j = s; j < e; ++j) {
                int sn = csr[j];
                float2 f = ((const float2*)(ff + (size_t)sn * D_DIM))[lane];
                a0 += f.x;
                a1 += f.y;
            }
        }
    }
    float sc = 1.0f / (float)(degn > 1 ? degn : 1);
    a0 *= sc; a1 *= sc;
    u32 outv = (u32)f2bf(a0) | ((u32)f2bf(a1) << 16);
    ((u32*)(agg + (size_t)node * D_DIM))[lane] = outv;
}

// --- K7: h = agg @ W^T + b (fp32 VALU), h written IN PLACE over agg ---------
// Each block: 64 rows x 128 cols. Thread t: cols c0=(t&63)*2, c0+1; rows
// rowgrp*16..+15. agg tile staged in LDS first (so in-place write is safe);
// LDS reads are wave-broadcast (all lanes same addr). Fused col sum/sumsq.
__global__ void k_gemm(u16* agg, const void* W, const void* bias,
                       float* colsum, float* colsq, const int* flag, int n) {
    __shared__ u16 sA[64 * 136];
    __shared__ float bsum[128], bsq[128];
    const int tid = threadIdx.x;
    const int rb = blockIdx.x * 64;
    const int bf = flag[0];
    if (tid < 128) { bsum[tid] = 0.f; bsq[tid] = 0.f; }
    for (int c = 0; c < 4; ++c) {                 // stage 64x128 bf16 tile
        int e = (c * 256 + tid) * 8;
        int row = e >> 7, k = e & 127;
        *(uint4*)(&sA[row * 136 + k]) = *(const uint4*)(agg + (size_t)rb * D_DIM + e);
    }
    __syncthreads();

    const int c0 = (tid & 63) * 2;
    const int rowgrp = tid >> 6;

    float acc0[16], acc1[16];
    for (int r = 0; r < 16; ++r) { acc0[r] = 0.f; acc1[r] = 0.f; }

    for (int kt = 0; kt < 16; ++kt) {             // 8 k-values per step
        float wf0[8], wf1[8];
        if (bf) {
            const uint4* Wv = (const uint4*)W;
            uint4 w0 = Wv[c0 * 16 + kt];
            uint4 w1 = Wv[(c0 + 1) * 16 + kt];
            wf0[0]=lo16(w0.x); wf0[1]=hi16(w0.x); wf0[2]=lo16(w0.y); wf0[3]=hi16(w0.y);
            wf0[4]=lo16(w0.z); wf0[5]=hi16(w0.z); wf0[6]=lo16(w0.w); wf0[7]=hi16(w0.w);
            wf1[0]=lo16(w1.x); wf1[1]=hi16(w1.x); wf1[2]=lo16(w1.y); wf1[3]=hi16(w1.y);
            wf1[4]=lo16(w1.z); wf1[5]=hi16(w1.z); wf1[6]=lo16(w1.w); wf1[7]=hi16(w1.w);
        } else {
            const float4* Wv = (const float4*)W;
            float4 a0v = Wv[c0 * 32 + kt * 2];
            float4 a1v = Wv[c0 * 32 + kt * 2 + 1];
            float4 b0v = Wv[(c0 + 1) * 32 + kt * 2];
            float4 b1v = Wv[(c0 + 1) * 32 + kt * 2 + 1];
            wf0[0]=a0v.x; wf0[1]=a0v.y; wf0[2]=a0v.z; wf0[3]=a0v.w;
            wf0[4]=a1v.x; wf0[5]=a1v.y; wf0[6]=a1v.z; wf0[7]=a1v.w;
            wf1[0]=b0v.x; wf1[1]=b0v.y; wf1[2]=b0v.z; wf1[3]=b0v.w;
            wf1[4]=b1v.x; wf1[5]=b1v.y; wf1[6]=b1v.z; wf1[7]=b1v.w;
        }
        for (int r = 0; r < 16; ++r) {
            uint4 av = *(const uint4*)(&sA[(rowgrp * 16 + r) * 136 + kt * 8]);
            float af[8];
            af[0]=lo16(av.x); af[1]=hi16(av.x); af[2]=lo16(av.y); af[3]=hi16(av.y);
            af[4]=lo16(av.z); af[5]=hi16(av.z); af[6]=lo16(av.w); af[7]=hi16(av.w);
            for (int j = 0; j < 8; ++j) {
                acc0[r] += af[j] * wf0[j];
                acc1[r] += af[j] * wf1[j];
            }
        }
    }

    float bv0, bv1;
    if (bf) { bv0 = bf2f(((const u16*)bias)[c0]); bv1 = bf2f(((const u16*)bias)[c0 + 1]); }
    else    { bv0 = ((const float*)bias)[c0];     bv1 = ((const float*)bias)[c0 + 1]; }
    float s0 = 0.f, q0 = 0.f, s1 = 0.f, q1 = 0.f;
    for (int r = 0; r < 16; ++r) {
        int row = rb + rowgrp * 16 + r;
        if (row < n) {
            float h0 = acc0[r] + bv0;
            float h1 = acc1[r] + bv1;
            u32 pk = (u32)f2bf(h0) | ((u32)f2bf(h1) << 16);
            *(u32*)(agg + (size_t)row * D_DIM + c0) = pk;   // h aliases agg
            s0 += h0; q0 += h0 * h0;
            s1 += h1; q1 += h1 * h1;
        }
    }
    atomicAdd(&bsum[c0], s0);
    atomicAdd(&bsq[c0], q0);
    atomicAdd(&bsum[c0 + 1], s1);
    atomicAdd(&bsq[c0 + 1], q1);
    __syncthreads();
    if (tid < 128) {
        atomicAdd(&colsum[tid], bsum[tid]);
        atomicAdd(&colsq[tid], bsq[tid]);
    }
}

// --- K8: BN stats -> per-column scale/shift ---------------------------------
__global__ void k_finalize(const float* stats, const void* gamma,
                           const void* beta, float* scsh, const int* flag,
                           float invn) {
    int t = threadIdx.x;
    int bf = flag[0];
    if (t < 128) {
        float mean = stats[t] * invn;
        float var = stats[128 + t] * invn - mean * mean;
        var = fmaxf(var, 0.f);
        float inv = rsqrtf(var + 1e-5f);
        float g = bf ? bf2f(((const u16*)gamma)[t]) : ((const float*)gamma)[t];
        float bb = bf ? bf2f(((const u16*)beta)[t]) : ((const float*)beta)[t];
        float sc = inv * g;
        float sh = bb - mean * sc;
        scsh[t] = sc;
        scsh[128 + t] = sh;
    }
}

// --- K9: out = feature + relu(h*scale + shift), dual dtype ------------------
__global__ void k_apply(const u16* h, const void* feature, const float* scsh,
                        void* outp, const int* flag, int total8) {
    __shared__ float ssc[128], ssh[128];
    int tid = threadIdx.x;
    if (tid < 128) { ssc[tid] = scsh[tid]; ssh[tid] = scsh[128 + tid]; }
    __syncthreads();
    int i = blockIdx.x * 256 + tid;
    if (i >= total8) return;
    int bf = flag[0];
    size_t base = (size_t)i * 8;
    int c0 = (int)(base & (D_DIM - 1));
    uint4 h4 = ((const uint4*)h)[i];
    u32 hw[4] = {h4.x, h4.y, h4.z, h4.w};
    float hv[8];
    for (int j = 0; j < 4; ++j) { hv[2*j] = lo16(hw[j]); hv[2*j+1] = hi16(hw[j]); }
    float fv[8];
    if (bf) {
        uint4 f4 = ((const uint4*)feature)[i];
        u32 fw[4] = {f4.x, f4.y, f4.z, f4.w};
        for (int j = 0; j < 4; ++j) { fv[2*j] = lo16(fw[j]); fv[2*j+1] = hi16(fw[j]); }
    } else {
        float4 fa = ((const float4*)feature)[i * 2];
        float4 fb = ((const float4*)feature)[i * 2 + 1];
        fv[0]=fa.x; fv[1]=fa.y; fv[2]=fa.z; fv[3]=fa.w;
        fv[4]=fb.x; fv[5]=fb.y; fv[6]=fb.z; fv[7]=fb.w;
    }
    float ov[8];
    for (int j = 0; j < 8; ++j)
        ov[j] = fmaxf(hv[j] * ssc[c0 + j] + ssh[c0 + j], 0.f) + fv[j];
    if (bf) {
        uint4 o4;
        u32 ow[4];
        for (int j = 0; j < 4; ++j)
            ow[j] = (u32)f2bf(ov[2*j]) | ((u32)f2bf(ov[2*j+1]) << 16);
        o4.x = ow[0]; o4.y = ow[1]; o4.z = ow[2]; o4.w = ow[3];
        ((uint4*)outp)[i] = o4;
    } else {
        float4 oa, ob;
        oa.x=ov[0]; oa.y=ov[1]; oa.z=ov[2]; oa.w=ov[3];
        ob.x=ov[4]; ob.y=ov[5]; ob.z=ov[6]; ob.w=ov[7];
        ((float4*)outp)[i * 2] = oa;
        ((float4*)outp)[i * 2 + 1] = ob;
    }
}

static inline size_t al256s(size_t x) { return (x + 255) & ~(size_t)255; }
static inline int gmax1(int x) { return x > 0 ? x : 1; }

extern "C" void kernel_launch(void* const* d_in, const int* in_sizes, int n_in,
                              void* d_out, int out_size, void* d_ws, size_t ws_size,
                              hipStream_t stream) {
    const void* feature = d_in[0];
    const int*  src     = (const int*)d_in[1];
    const int*  dst     = (const int*)d_in[2];
    const void* W       = d_in[3];
    const void* bias    = d_in[4];
    const void* gamma   = d_in[5];
    const void* beta    = d_in[6];

    const int N = in_sizes[0] / D_DIM;
    const int E = in_sizes[1];
    const int Npad = (N + 63) & ~63;
    const int nIter = (N + 4095) / 4096;

    char* p = (char*)d_ws;
    size_t o = 0;
    int*   flag   = (int*)(p + o);      o += 256;
    int*   deg    = (int*)(p + o);      o += (size_t)N * 4;
    float* stats  = (float*)(p + o);    o += 256 * 4;           // sum[128],sq[128]
    const int zero_words = N + 256;                              // deg+stats contiguous
    o = al256s(o);
    float* scsh   = (float*)(p + o);    o += al256s(256 * 4);
    int*   offs   = (int*)(p + o);      o += al256s(((size_t)N + 8) * 4);
    int*   cursor = (int*)(p + o);      o += al256s(((size_t)N + 8) * 4);
    int*   csr    = (int*)(p + o);      o += al256s((size_t)E * 4);
    u16*   agg    = (u16*)(p + o);      o += al256s((size_t)Npad * D_DIM * 2);
    (void)ws_size; (void)n_in;

    int eb = gmax1((E + 255) / 256);
    int ob = gmax1((out_size + 255) / 256);
    int total8 = N * D_DIM / 8;

    k_detect<<<1, 256, 0, stream>>>((const u32*)feature, flag);
    k_fill<<<ob, 256, 0, stream>>>((u32*)d_out, flag, out_size);
    GCNLayer_76647986365164_kernel<<<gmax1((zero_words + 255) / 256), 256, 0, stream>>>(deg, zero_words);
    k_deg<<<eb, 256, 0, stream>>>(dst, deg, E);
    k_scan<<<1, 256, 0, stream>>>(deg, offs, cursor, N, nIter);
    k_scatter<<<eb, 256, 0, stream>>>(src, dst, cursor, csr, E);
    k_aggregate<<<gmax1(Npad / 4), 256, 0, stream>>>(feature, offs, csr, agg, flag, N, Npad);
    k_gemm<<<gmax1(Npad / 64), 256, 0, stream>>>(agg, W, bias, stats, stats + 128, flag, N);
    k_finalize<<<1, 128, 0, stream>>>(stats, gamma, beta, scsh, flag, 1.0f / (float)N);
    k_apply<<<gmax1((total8 + 255) / 256), 256, 0, stream>>>(agg, feature, scsh, d_out, flag, total8);
}

// Round 5
// 444.797 us; speedup vs baseline: 1.3337x; 1.3337x over previous
//
#include <hip/hip_runtime.h>

typedef unsigned short u16;
typedef unsigned int u32;

#define D_DIM 128
#define CHUNK 4096   // elements scanned per block (256 threads x 16)

__device__ __forceinline__ float bf2f(u16 h) {
    u32 u = ((u32)h) << 16;
    return __uint_as_float(u);
}
__device__ __forceinline__ u16 f2bf(float f) {
    u32 u = __float_as_uint(f);
    u32 r = (u >> 16) & 1u;
    u += 0x7fffu + r;                 // round-to-nearest-even
    return (u16)(u >> 16);
}
__device__ __forceinline__ float lo16(u32 u) { return bf2f((u16)(u & 0xffffu)); }
__device__ __forceinline__ float hi16(u32 u) { return bf2f((u16)(u >> 16)); }

// --- K0: dtype detector (bf16 vs fp32 packing of the float tensors) ---------
__global__ void k_detect(const u32* w, int* flag) {
    __shared__ int cnt;
    if (threadIdx.x == 0) cnt = 0;
    __syncthreads();
    int c = 0;
    for (int j = 0; j < 4; ++j) {
        u32 x = w[threadIdx.x * 4 + j];
        u32 e = (x >> 7) & 0xFFu;
        if (e >= 100u && e <= 140u) c++;
    }
    atomicAdd(&cnt, c);
    __syncthreads();
    if (threadIdx.x == 0) flag[0] = (cnt >= 700) ? 1 : 0;
}

// --- K1: zero scratch words (harness's expected symbol name kept) -----------
__global__ void GCNLayer_76647986365164_kernel(int* p, int nwords) {
    int i = blockIdx.x * blockDim.x + threadIdx.x;
    if (i < nwords) p[i] = 0;
}

// --- K2: in-degree count ----------------------------------------------------
__global__ void k_deg(const int* dst, int* deg, int E) {
    int i = blockIdx.x * blockDim.x + threadIdx.x;
    if (i < E) atomicAdd(&deg[dst[i]], 1);
}

// --- K3a: block-local exclusive scan (multi-block; LDS Hillis-Steele) -------
// Block b scans deg[b*CHUNK .. b*CHUNK+CHUNK) into offs (local prefixes) and
// writes the block total to bsums[b].
__global__ void k_scan_local(const int* deg, int* offs, int* bsums, int n) {
    __shared__ int tsum[256];
    const int tid = threadIdx.x;
    const int base = blockIdx.x * CHUNK + tid * 16;
    int v[16];
    int run = 0;
    for (int j = 0; j < 16; ++j) {
        int idx = base + j;
        v[j] = (idx < n) ? deg[idx] : 0;
        run += v[j];
    }
    tsum[tid] = run;
    __syncthreads();
    for (int off = 1; off < 256; off <<= 1) {      // inclusive scan of thread sums
        int val = tsum[tid];
        int add = (tid >= off) ? tsum[tid - off] : 0;
        __syncthreads();
        tsum[tid] = val + add;
        __syncthreads();
    }
    int acc = tsum[tid] - run;                     // exclusive start (local)
    for (int j = 0; j < 16; ++j) {
        int idx = base + j;
        if (idx < n) offs[idx] = acc;
        acc += v[j];
    }
    if (tid == 255) bsums[blockIdx.x] = tsum[255];
}

// --- K3b: add scanned block totals; emit final offs + cursor ----------------
__global__ void k_scan_add(int* offs, int* cursor, const int* bsums,
                           int n, int nblk) {
    __shared__ int carry_s;
    const int tid = threadIdx.x;
    const int b = blockIdx.x;
    if (tid == 0) {
        int c = 0;
        for (int i = 0; i < b; ++i) c += bsums[i];
        carry_s = c;
        if (b == nblk - 1) offs[n] = c + bsums[b];   // total == E
    }
    __syncthreads();
    const int carry = carry_s;
    const int base = b * CHUNK + tid * 16;
    for (int j = 0; j < 16; ++j) {
        int idx = base + j;
        if (idx < n) {
            int val = offs[idx] + carry;
            offs[idx] = val;
            cursor[idx] = val;
        }
    }
}

// --- K4: scatter edges into CSR buckets -------------------------------------
__global__ void k_scatter(const int* src, const int* dst,
                          int* cursor, int* csr, int E) {
    int i = blockIdx.x * blockDim.x + threadIdx.x;
    if (i < E) {
        int d = dst[i];
        int pos = atomicAdd(&cursor[d], 1);
        csr[pos] = src[i];
    }
}

// --- K5: gather-reduce mean aggregation, one wave per node, dual dtype ------
__global__ void k_aggregate(const void* feature, const int* offs,
                            const int* csr, u16* agg, const int* flag,
                            int n, int npad) {
    int node = blockIdx.x * 4 + (threadIdx.x >> 6);
    int lane = threadIdx.x & 63;
    if (node >= npad) return;
    int bf = flag[0];
    float a0 = 0.f, a1 = 0.f;
    int degn = 0;
    if (node < n) {
        int s = offs[node], e = offs[node + 1];
        degn = e - s;
        if (bf) {
            const u16* f16 = (const u16*)feature;
            for (int j = s; j < e; ++j) {
                int sn = csr[j];
                u32 u = ((const u32*)(f16 + (size_t)sn * D_DIM))[lane];
                a0 += lo16(u);
                a1 += hi16(u);
            }
        } else {
            const float* ff = (const float*)feature;
            for (int j = s; j < e; ++j) {
                int sn = csr[j];
                float2 f = ((const float2*)(ff + (size_t)sn * D_DIM))[lane];
                a0 += f.x;
                a1 += f.y;
            }
        }
    }
    float sc = 1.0f / (float)(degn > 1 ? degn : 1);
    a0 *= sc; a1 *= sc;
    u32 outv = (u32)f2bf(a0) | ((u32)f2bf(a1) << 16);
    ((u32*)(agg + (size_t)node * D_DIM))[lane] = outv;
}

// --- K6: h = agg @ W^T + b (fp32 VALU), h written IN PLACE over agg ---------
__global__ void k_gemm(u16* agg, const void* W, const void* bias,
                       float* colsum, float* colsq, const int* flag, int n) {
    __shared__ u16 sA[64 * 136];
    __shared__ float bsum[128], bsq[128];
    const int tid = threadIdx.x;
    const int rb = blockIdx.x * 64;
    const int bf = flag[0];
    if (tid < 128) { bsum[tid] = 0.f; bsq[tid] = 0.f; }
    for (int c = 0; c < 4; ++c) {                 // stage 64x128 bf16 tile
        int e = (c * 256 + tid) * 8;
        int row = e >> 7, k = e & 127;
        *(uint4*)(&sA[row * 136 + k]) = *(const uint4*)(agg + (size_t)rb * D_DIM + e);
    }
    __syncthreads();

    const int c0 = (tid & 63) * 2;
    const int rowgrp = tid >> 6;

    float acc0[16], acc1[16];
    for (int r = 0; r < 16; ++r) { acc0[r] = 0.f; acc1[r] = 0.f; }

    for (int kt = 0; kt < 16; ++kt) {             // 8 k-values per step
        float wf0[8], wf1[8];
        if (bf) {
            const uint4* Wv = (const uint4*)W;
            uint4 w0 = Wv[c0 * 16 + kt];
            uint4 w1 = Wv[(c0 + 1) * 16 + kt];
            wf0[0]=lo16(w0.x); wf0[1]=hi16(w0.x); wf0[2]=lo16(w0.y); wf0[3]=hi16(w0.y);
            wf0[4]=lo16(w0.z); wf0[5]=hi16(w0.z); wf0[6]=lo16(w0.w); wf0[7]=hi16(w0.w);
            wf1[0]=lo16(w1.x); wf1[1]=hi16(w1.x); wf1[2]=lo16(w1.y); wf1[3]=hi16(w1.y);
            wf1[4]=lo16(w1.z); wf1[5]=hi16(w1.z); wf1[6]=lo16(w1.w); wf1[7]=hi16(w1.w);
        } else {
            const float4* Wv = (const float4*)W;
            float4 a0v = Wv[c0 * 32 + kt * 2];
            float4 a1v = Wv[c0 * 32 + kt * 2 + 1];
            float4 b0v = Wv[(c0 + 1) * 32 + kt * 2];
            float4 b1v = Wv[(c0 + 1) * 32 + kt * 2 + 1];
            wf0[0]=a0v.x; wf0[1]=a0v.y; wf0[2]=a0v.z; wf0[3]=a0v.w;
            wf0[4]=a1v.x; wf0[5]=a1v.y; wf0[6]=a1v.z; wf0[7]=a1v.w;
            wf1[0]=b0v.x; wf1[1]=b0v.y; wf1[2]=b0v.z; wf1[3]=b0v.w;
            wf1[4]=b1v.x; wf1[5]=b1v.y; wf1[6]=b1v.z; wf1[7]=b1v.w;
        }
        for (int r = 0; r < 16; ++r) {
            uint4 av = *(const uint4*)(&sA[(rowgrp * 16 + r) * 136 + kt * 8]);
            float af[8];
            af[0]=lo16(av.x); af[1]=hi16(av.x); af[2]=lo16(av.y); af[3]=hi16(av.y);
            af[4]=lo16(av.z); af[5]=hi16(av.z); af[6]=lo16(av.w); af[7]=hi16(av.w);
            for (int j = 0; j < 8; ++j) {
                acc0[r] += af[j] * wf0[j];
                acc1[r] += af[j] * wf1[j];
            }
        }
    }

    float bv0, bv1;
    if (bf) { bv0 = bf2f(((const u16*)bias)[c0]); bv1 = bf2f(((const u16*)bias)[c0 + 1]); }
    else    { bv0 = ((const float*)bias)[c0];     bv1 = ((const float*)bias)[c0 + 1]; }
    float s0 = 0.f, q0 = 0.f, s1 = 0.f, q1 = 0.f;
    for (int r = 0; r < 16; ++r) {
        int row = rb + rowgrp * 16 + r;
        if (row < n) {
            float h0 = acc0[r] + bv0;
            float h1 = acc1[r] + bv1;
            u32 pk = (u32)f2bf(h0) | ((u32)f2bf(h1) << 16);
            *(u32*)(agg + (size_t)row * D_DIM + c0) = pk;   // h aliases agg
            s0 += h0; q0 += h0 * h0;
            s1 += h1; q1 += h1 * h1;
        }
    }
    atomicAdd(&bsum[c0], s0);
    atomicAdd(&bsq[c0], q0);
    atomicAdd(&bsum[c0 + 1], s1);
    atomicAdd(&bsq[c0 + 1], q1);
    __syncthreads();
    if (tid < 128) {
        atomicAdd(&colsum[tid], bsum[tid]);
        atomicAdd(&colsq[tid], bsq[tid]);
    }
}

// --- K7: BN stats -> per-column scale/shift ---------------------------------
__global__ void k_finalize(const float* stats, const void* gamma,
                           const void* beta, float* scsh, const int* flag,
                           float invn) {
    int t = threadIdx.x;
    int bf = flag[0];
    if (t < 128) {
        float mean = stats[t] * invn;
        float var = stats[128 + t] * invn - mean * mean;
        var = fmaxf(var, 0.f);
        float inv = rsqrtf(var + 1e-5f);
        float g = bf ? bf2f(((const u16*)gamma)[t]) : ((const float*)gamma)[t];
        float bb = bf ? bf2f(((const u16*)beta)[t]) : ((const float*)beta)[t];
        float sc = inv * g;
        float sh = bb - mean * sc;
        scsh[t] = sc;
        scsh[128 + t] = sh;
    }
}

// --- K8: out = feature + relu(h*scale + shift), dual dtype ------------------
__global__ void k_apply(const u16* h, const void* feature, const float* scsh,
                        void* outp, const int* flag, int total8) {
    __shared__ float ssc[128], ssh[128];
    int tid = threadIdx.x;
    if (tid < 128) { ssc[tid] = scsh[tid]; ssh[tid] = scsh[128 + tid]; }
    __syncthreads();
    int i = blockIdx.x * 256 + tid;
    if (i >= total8) return;
    int bf = flag[0];
    size_t base = (size_t)i * 8;
    int c0 = (int)(base & (D_DIM - 1));
    uint4 h4 = ((const uint4*)h)[i];
    u32 hw[4] = {h4.x, h4.y, h4.z, h4.w};
    float hv[8];
    for (int j = 0; j < 4; ++j) { hv[2*j] = lo16(hw[j]); hv[2*j+1] = hi16(hw[j]); }
    float fv[8];
    if (bf) {
        uint4 f4 = ((const uint4*)feature)[i];
        u32 fw[4] = {f4.x, f4.y, f4.z, f4.w};
        for (int j = 0; j < 4; ++j) { fv[2*j] = lo16(fw[j]); fv[2*j+1] = hi16(fw[j]); }
    } else {
        float4 fa = ((const float4*)feature)[i * 2];
        float4 fb = ((const float4*)feature)[i * 2 + 1];
        fv[0]=fa.x; fv[1]=fa.y; fv[2]=fa.z; fv[3]=fa.w;
        fv[4]=fb.x; fv[5]=fb.y; fv[6]=fb.z; fv[7]=fb.w;
    }
    float ov[8];
    for (int j = 0; j < 8; ++j)
        ov[j] = fmaxf(hv[j] * ssc[c0 + j] + ssh[c0 + j], 0.f) + fv[j];
    if (bf) {
        uint4 o4;
        u32 ow[4];
        for (int j = 0; j < 4; ++j)
            ow[j] = (u32)f2bf(ov[2*j]) | ((u32)f2bf(ov[2*j+1]) << 16);
        o4.x = ow[0]; o4.y = ow[1]; o4.z = ow[2]; o4.w = ow[3];
        ((uint4*)outp)[i] = o4;
    } else {
        float4 oa, ob;
        oa.x=ov[0]; oa.y=ov[1]; oa.z=ov[2]; oa.w=ov[3];
        ob.x=ov[4]; ob.y=ov[5]; ob.z=ov[6]; ob.w=ov[7];
        ((float4*)outp)[i * 2] = oa;
        ((float4*)outp)[i * 2 + 1] = ob;
    }
}

static inline size_t al256s(size_t x) { return (x + 255) & ~(size_t)255; }
static inline int gmax1(int x) { return x > 0 ? x : 1; }

extern "C" void kernel_launch(void* const* d_in, const int* in_sizes, int n_in,
                              void* d_out, int out_size, void* d_ws, size_t ws_size,
                              hipStream_t stream) {
    const void* feature = d_in[0];
    const int*  src     = (const int*)d_in[1];
    const int*  dst     = (const int*)d_in[2];
    const void* W       = d_in[3];
    const void* bias    = d_in[4];
    const void* gamma   = d_in[5];
    const void* beta    = d_in[6];

    const int N = in_sizes[0] / D_DIM;
    const int E = in_sizes[1];
    const int Npad = (N + 63) & ~63;
    const int nblk = (N + CHUNK - 1) / CHUNK;      // scan blocks

    char* p = (char*)d_ws;
    size_t o = 0;
    int*   flag   = (int*)(p + o);      o += 256;
    int*   deg    = (int*)(p + o);      o += (size_t)N * 4;
    float* stats  = (float*)(p + o);    o += 256 * 4;           // sum[128],sq[128]
    const int zero_words = N + 256;                              // deg+stats contiguous
    o = al256s(o);
    float* scsh   = (float*)(p + o);    o += al256s(256 * 4);
    int*   bsums  = (int*)(p + o);      o += al256s(((size_t)nblk + 8) * 4);
    int*   offs   = (int*)(p + o);      o += al256s(((size_t)N + 8) * 4);
    int*   cursor = (int*)(p + o);      o += al256s(((size_t)N + 8) * 4);
    int*   csr    = (int*)(p + o);      o += al256s((size_t)E * 4);
    u16*   agg    = (u16*)(p + o);      o += al256s((size_t)Npad * D_DIM * 2);
    (void)ws_size; (void)n_in; (void)out_size;

    int eb = gmax1((E + 255) / 256);
    int total8 = N * D_DIM / 8;

    k_detect<<<1, 256, 0, stream>>>((const u32*)feature, flag);
    GCNLayer_76647986365164_kernel<<<gmax1((zero_words + 255) / 256), 256, 0, stream>>>(deg, zero_words);
    k_deg<<<eb, 256, 0, stream>>>(dst, deg, E);
    k_scan_local<<<gmax1(nblk), 256, 0, stream>>>(deg, offs, bsums, N);
    k_scan_add<<<gmax1(nblk), 256, 0, stream>>>(offs, cursor, bsums, N, nblk);
    k_scatter<<<eb, 256, 0, stream>>>(src, dst, cursor, csr, E);
    k_aggregate<<<gmax1(Npad / 4), 256, 0, stream>>>(feature, offs, csr, agg, flag, N, Npad);
    k_gemm<<<gmax1(Npad / 64), 256, 0, stream>>>(agg, W, bias, stats, stats + 128, flag, N);
    k_finalize<<<1, 128, 0, stream>>>(stats, gamma, beta, scsh, flag, 1.0f / (float)N);
    k_apply<<<gmax1((total8 + 255) / 256), 256, 0, stream>>>(agg, feature, scsh, d_out, flag, total8);
}

// Round 7
// 405.136 us; speedup vs baseline: 1.4642x; 1.0979x over previous
//
#include <hip/hip_runtime.h>

typedef unsigned short u16;
typedef unsigned int u32;

#define D_DIM 128
#define CHUNK 4096   // elements scanned per block (256 threads x 16)

__device__ __forceinline__ float bf2f(u16 h) {
    u32 u = ((u32)h) << 16;
    return __uint_as_float(u);
}
__device__ __forceinline__ u16 f2bf(float f) {
    u32 u = __float_as_uint(f);
    u32 r = (u >> 16) & 1u;
    u += 0x7fffu + r;                 // round-to-nearest-even
    return (u16)(u >> 16);
}
__device__ __forceinline__ float lo16(u32 u) { return bf2f((u16)(u & 0xffffu)); }
__device__ __forceinline__ float hi16(u32 u) { return bf2f((u16)(u >> 16)); }

// --- K0: dtype detector (bf16 vs fp32 packing of the float tensors) ---------
__global__ void k_detect(const u32* w, int* flag) {
    __shared__ int cnt;
    if (threadIdx.x == 0) cnt = 0;
    __syncthreads();
    int c = 0;
    for (int j = 0; j < 4; ++j) {
        u32 x = w[threadIdx.x * 4 + j];
        u32 e = (x >> 7) & 0xFFu;
        if (e >= 100u && e <= 140u) c++;
    }
    atomicAdd(&cnt, c);
    __syncthreads();
    if (threadIdx.x == 0) flag[0] = (cnt >= 700) ? 1 : 0;
}

// --- K1: zero scratch words (harness's expected symbol name kept) -----------
__global__ void GCNLayer_76647986365164_kernel(int* p, int nwords) {
    int i = blockIdx.x * blockDim.x + threadIdx.x;
    if (i < nwords) p[i] = 0;
}

// --- K2: in-degree count ----------------------------------------------------
__global__ void k_deg(const int* dst, int* deg, int E) {
    int i = blockIdx.x * blockDim.x + threadIdx.x;
    if (i < E) atomicAdd(&deg[dst[i]], 1);
}

// --- K3a: block-local exclusive scan (multi-block; LDS Hillis-Steele) -------
__global__ void k_scan_local(const int* deg, int* offs, int* bsums, int n) {
    __shared__ int tsum[256];
    const int tid = threadIdx.x;
    const int base = blockIdx.x * CHUNK + tid * 16;
    int v[16];
    int run = 0;
    for (int j = 0; j < 16; ++j) {
        int idx = base + j;
        v[j] = (idx < n) ? deg[idx] : 0;
        run += v[j];
    }
    tsum[tid] = run;
    __syncthreads();
    for (int off = 1; off < 256; off <<= 1) {      // inclusive scan of thread sums
        int val = tsum[tid];
        int add = (tid >= off) ? tsum[tid - off] : 0;
        __syncthreads();
        tsum[tid] = val + add;
        __syncthreads();
    }
    int acc = tsum[tid] - run;                     // exclusive start (local)
    for (int j = 0; j < 16; ++j) {
        int idx = base + j;
        if (idx < n) offs[idx] = acc;
        acc += v[j];
    }
    if (tid == 255) bsums[blockIdx.x] = tsum[255];
}

// --- K3b: add scanned block totals; emit final offs + cursor ----------------
__global__ void k_scan_add(int* offs, int* cursor, const int* bsums,
                           int n, int nblk) {
    __shared__ int carry_s;
    const int tid = threadIdx.x;
    const int b = blockIdx.x;
    if (tid == 0) {
        int c = 0;
        for (int i = 0; i < b; ++i) c += bsums[i];
        carry_s = c;
        if (b == nblk - 1) offs[n] = c + bsums[b];   // total == E
    }
    __syncthreads();
    const int carry = carry_s;
    const int base = b * CHUNK + tid * 16;
    for (int j = 0; j < 16; ++j) {
        int idx = base + j;
        if (idx < n) {
            int val = offs[idx] + carry;
            offs[idx] = val;
            cursor[idx] = val;
        }
    }
}

// --- K4: scatter edges into CSR buckets -------------------------------------
__global__ void k_scatter(const int* src, const int* dst,
                          int* cursor, int* csr, int E) {
    int i = blockIdx.x * blockDim.x + threadIdx.x;
    if (i < E) {
        int d = dst[i];
        int pos = atomicAdd(&cursor[d], 1);
        csr[pos] = src[i];
    }
}

// --- K5: gather-reduce mean aggregation, one wave per node ------------------
// 2-stage software pipeline, SINGLE accumulator pair: identical summation
// order to the green R5 build (only instruction scheduling differs), but the
// next edge's feature row load is issued before the current row is consumed
// (~2 outstanding loads vs R5's ~1; R5 was latency-bound at 2.27 TB/s).
__global__ void k_aggregate(const void* feature, const int* offs,
                            const int* csr, u16* agg, const int* flag,
                            int n, int npad) {
    int node = blockIdx.x * 4 + (threadIdx.x >> 6);
    int lane = threadIdx.x & 63;
    if (node >= npad) return;
    int bf = flag[0];
    float a0 = 0.f, a1 = 0.f;
    int degn = 0;
    if (node < n) {
        int s = offs[node], e = offs[node + 1];
        degn = e - s;
        if (bf) {
            const u32* fw = (const u32*)feature;      // row stride 64 words
            if (s < e) {
                u32 u = fw[(size_t)csr[s] * 64 + lane];
                for (int j = s + 1; j < e; ++j) {
                    u32 unext = fw[(size_t)csr[j] * 64 + lane];  // in flight…
                    a0 += lo16(u);                                // …while adding
                    a1 += hi16(u);
                    u = unext;
                }
                a0 += lo16(u);
                a1 += hi16(u);
            }
        } else {
            const float2* f2 = (const float2*)feature;  // row stride 64 float2
            if (s < e) {
                float2 u = f2[(size_t)csr[s] * 64 + lane];
                for (int j = s + 1; j < e; ++j) {
                    float2 unext = f2[(size_t)csr[j] * 64 + lane];
                    a0 += u.x;
                    a1 += u.y;
                    u = unext;
                }
                a0 += u.x;
                a1 += u.y;
            }
        }
    }
    float sc = 1.0f / (float)(degn > 1 ? degn : 1);
    a0 *= sc; a1 *= sc;
    u32 outv = (u32)f2bf(a0) | ((u32)f2bf(a1) << 16);
    ((u32*)(agg + (size_t)node * D_DIM))[lane] = outv;
}

// --- K6: h = agg @ W^T + b (fp32 VALU), h written IN PLACE over agg ---------
__global__ void k_gemm(u16* agg, const void* W, const void* bias,
                       float* colsum, float* colsq, const int* flag, int n) {
    __shared__ u16 sA[64 * 136];
    __shared__ float bsum[128], bsq[128];
    const int tid = threadIdx.x;
    const int rb = blockIdx.x * 64;
    const int bf = flag[0];
    if (tid < 128) { bsum[tid] = 0.f; bsq[tid] = 0.f; }
    for (int c = 0; c < 4; ++c) {                 // stage 64x128 bf16 tile
        int e = (c * 256 + tid) * 8;
        int row = e >> 7, k = e & 127;
        *(uint4*)(&sA[row * 136 + k]) = *(const uint4*)(agg + (size_t)rb * D_DIM + e);
    }
    __syncthreads();

    const int c0 = (tid & 63) * 2;
    const int rowgrp = tid >> 6;

    float acc0[16], acc1[16];
    for (int r = 0; r < 16; ++r) { acc0[r] = 0.f; acc1[r] = 0.f; }

    for (int kt = 0; kt < 16; ++kt) {             // 8 k-values per step
        float wf0[8], wf1[8];
        if (bf) {
            const uint4* Wv = (const uint4*)W;
            uint4 w0 = Wv[c0 * 16 + kt];
            uint4 w1 = Wv[(c0 + 1) * 16 + kt];
            wf0[0]=lo16(w0.x); wf0[1]=hi16(w0.x); wf0[2]=lo16(w0.y); wf0[3]=hi16(w0.y);
            wf0[4]=lo16(w0.z); wf0[5]=hi16(w0.z); wf0[6]=lo16(w0.w); wf0[7]=hi16(w0.w);
            wf1[0]=lo16(w1.x); wf1[1]=hi16(w1.x); wf1[2]=lo16(w1.y); wf1[3]=hi16(w1.y);
            wf1[4]=lo16(w1.z); wf1[5]=hi16(w1.z); wf1[6]=lo16(w1.w); wf1[7]=hi16(w1.w);
        } else {
            const float4* Wv = (const float4*)W;
            float4 a0v = Wv[c0 * 32 + kt * 2];
            float4 a1v = Wv[c0 * 32 + kt * 2 + 1];
            float4 b0v = Wv[(c0 + 1) * 32 + kt * 2];
            float4 b1v = Wv[(c0 + 1) * 32 + kt * 2 + 1];
            wf0[0]=a0v.x; wf0[1]=a0v.y; wf0[2]=a0v.z; wf0[3]=a0v.w;
            wf0[4]=a1v.x; wf0[5]=a1v.y; wf0[6]=a1v.z; wf0[7]=a1v.w;
            wf1[0]=b0v.x; wf1[1]=b0v.y; wf1[2]=b0v.z; wf1[3]=b0v.w;
            wf1[4]=b1v.x; wf1[5]=b1v.y; wf1[6]=b1v.z; wf1[7]=b1v.w;
        }
        for (int r = 0; r < 16; ++r) {
            uint4 av = *(const uint4*)(&sA[(rowgrp * 16 + r) * 136 + kt * 8]);
            float af[8];
            af[0]=lo16(av.x); af[1]=hi16(av.x); af[2]=lo16(av.y); af[3]=hi16(av.y);
            af[4]=lo16(av.z); af[5]=hi16(av.z); af[6]=lo16(av.w); af[7]=hi16(av.w);
            for (int j = 0; j < 8; ++j) {
                acc0[r] += af[j] * wf0[j];
                acc1[r] += af[j] * wf1[j];
            }
        }
    }

    float bv0, bv1;
    if (bf) { bv0 = bf2f(((const u16*)bias)[c0]); bv1 = bf2f(((const u16*)bias)[c0 + 1]); }
    else    { bv0 = ((const float*)bias)[c0];     bv1 = ((const float*)bias)[c0 + 1]; }
    float s0 = 0.f, q0 = 0.f, s1 = 0.f, q1 = 0.f;
    for (int r = 0; r < 16; ++r) {
        int row = rb + rowgrp * 16 + r;
        if (row < n) {
            float h0 = acc0[r] + bv0;
            float h1 = acc1[r] + bv1;
            u32 pk = (u32)f2bf(h0) | ((u32)f2bf(h1) << 16);
            *(u32*)(agg + (size_t)row * D_DIM + c0) = pk;   // h aliases agg
            s0 += h0; q0 += h0 * h0;
            s1 += h1; q1 += h1 * h1;
        }
    }
    atomicAdd(&bsum[c0], s0);
    atomicAdd(&bsq[c0], q0);
    atomicAdd(&bsum[c0 + 1], s1);
    atomicAdd(&bsq[c0 + 1], q1);
    __syncthreads();
    if (tid < 128) {
        atomicAdd(&colsum[tid], bsum[tid]);
        atomicAdd(&colsq[tid], bsq[tid]);
    }
}

// --- K7: BN stats -> per-column scale/shift ---------------------------------
__global__ void k_finalize(const float* stats, const void* gamma,
                           const void* beta, float* scsh, const int* flag,
                           float invn) {
    int t = threadIdx.x;
    int bf = flag[0];
    if (t < 128) {
        float mean = stats[t] * invn;
        float var = stats[128 + t] * invn - mean * mean;
        var = fmaxf(var, 0.f);
        float inv = rsqrtf(var + 1e-5f);
        float g = bf ? bf2f(((const u16*)gamma)[t]) : ((const float*)gamma)[t];
        float bb = bf ? bf2f(((const u16*)beta)[t]) : ((const float*)beta)[t];
        float sc = inv * g;
        float sh = bb - mean * sc;
        scsh[t] = sc;
        scsh[128 + t] = sh;
    }
}

// --- K8: out = feature + relu(h*scale + shift), dual dtype ------------------
__global__ void k_apply(const u16* h, const void* feature, const float* scsh,
                        void* outp, const int* flag, int total8) {
    __shared__ float ssc[128], ssh[128];
    int tid = threadIdx.x;
    if (tid < 128) { ssc[tid] = scsh[tid]; ssh[tid] = scsh[128 + tid]; }
    __syncthreads();
    int i = blockIdx.x * 256 + tid;
    if (i >= total8) return;
    int bf = flag[0];
    size_t base = (size_t)i * 8;
    int c0 = (int)(base & (D_DIM - 1));
    uint4 h4 = ((const uint4*)h)[i];
    u32 hw[4] = {h4.x, h4.y, h4.z, h4.w};
    float hv[8];
    for (int j = 0; j < 4; ++j) { hv[2*j] = lo16(hw[j]); hv[2*j+1] = hi16(hw[j]); }
    float fv[8];
    if (bf) {
        uint4 f4 = ((const uint4*)feature)[i];
        u32 fw[4] = {f4.x, f4.y, f4.z, f4.w};
        for (int j = 0; j < 4; ++j) { fv[2*j] = lo16(fw[j]); fv[2*j+1] = hi16(fw[j]); }
    } else {
        float4 fa = ((const float4*)feature)[i * 2];
        float4 fb = ((const float4*)feature)[i * 2 + 1];
        fv[0]=fa.x; fv[1]=fa.y; fv[2]=fa.z; fv[3]=fa.w;
        fv[4]=fb.x; fv[5]=fb.y; fv[6]=fb.z; fv[7]=fb.w;
    }
    float ov[8];
    for (int j = 0; j < 8; ++j)
        ov[j] = fmaxf(hv[j] * ssc[c0 + j] + ssh[c0 + j], 0.f) + fv[j];
    if (bf) {
        uint4 o4;
        u32 ow[4];
        for (int j = 0; j < 4; ++j)
            ow[j] = (u32)f2bf(ov[2*j]) | ((u32)f2bf(ov[2*j+1]) << 16);
        o4.x = ow[0]; o4.y = ow[1]; o4.z = ow[2]; o4.w = ow[3];
        ((uint4*)outp)[i] = o4;
    } else {
        float4 oa, ob;
        oa.x=ov[0]; oa.y=ov[1]; oa.z=ov[2]; oa.w=ov[3];
        ob.x=ov[4]; ob.y=ov[5]; ob.z=ov[6]; ob.w=ov[7];
        ((float4*)outp)[i * 2] = oa;
        ((float4*)outp)[i * 2 + 1] = ob;
    }
}

static inline size_t al256s(size_t x) { return (x + 255) & ~(size_t)255; }
static inline int gmax1(int x) { return x > 0 ? x : 1; }

extern "C" void kernel_launch(void* const* d_in, const int* in_sizes, int n_in,
                              void* d_out, int out_size, void* d_ws, size_t ws_size,
                              hipStream_t stream) {
    const void* feature = d_in[0];
    const int*  src     = (const int*)d_in[1];
    const int*  dst     = (const int*)d_in[2];
    const void* W       = d_in[3];
    const void* bias    = d_in[4];
    const void* gamma   = d_in[5];
    const void* beta    = d_in[6];

    const int N = in_sizes[0] / D_DIM;
    const int E = in_sizes[1];
    const int Npad = (N + 63) & ~63;
    const int nblk = (N + CHUNK - 1) / CHUNK;      // scan blocks

    char* p = (char*)d_ws;
    size_t o = 0;
    int*   flag   = (int*)(p + o);      o += 256;
    int*   deg    = (int*)(p + o);      o += (size_t)N * 4;
    float* stats  = (float*)(p + o);    o += 256 * 4;           // sum[128],sq[128]
    const int zero_words = N + 256;                              // deg+stats contiguous
    o = al256s(o);
    float* scsh   = (float*)(p + o);    o += al256s(256 * 4);
    int*   bsums  = (int*)(p + o);      o += al256s(((size_t)nblk + 8) * 4);
    int*   offs   = (int*)(p + o);      o += al256s(((size_t)N + 8) * 4);
    int*   cursor = (int*)(p + o);      o += al256s(((size_t)N + 8) * 4);
    int*   csr    = (int*)(p + o);      o += al256s((size_t)E * 4);
    u16*   agg    = (u16*)(p + o);      o += al256s((size_t)Npad * D_DIM * 2);
    (void)ws_size; (void)n_in; (void)out_size;

    int eb = gmax1((E + 255) / 256);
    int total8 = N * D_DIM / 8;

    k_detect<<<1, 256, 0, stream>>>((const u32*)feature, flag);
    GCNLayer_76647986365164_kernel<<<gmax1((zero_words + 255) / 256), 256, 0, stream>>>(deg, zero_words);
    k_deg<<<eb, 256, 0, stream>>>(dst, deg, E);
    k_scan_local<<<gmax1(nblk), 256, 0, stream>>>(deg, offs, bsums, N);
    k_scan_add<<<gmax1(nblk), 256, 0, stream>>>(offs, cursor, bsums, N, nblk);
    k_scatter<<<eb, 256, 0, stream>>>(src, dst, cursor, csr, E);
    k_aggregate<<<gmax1(Npad / 4), 256, 0, stream>>>(feature, offs, csr, agg, flag, N, Npad);
    k_gemm<<<gmax1(Npad / 64), 256, 0, stream>>>(agg, W, bias, stats, stats + 128, flag, N);
    k_finalize<<<1, 128, 0, stream>>>(stats, gamma, beta, scsh, flag, 1.0f / (float)N);
    k_apply<<<gmax1((total8 + 255) / 256), 256, 0, stream>>>(agg, feature, scsh, d_out, flag, total8);
}